// Round 12
// baseline (330.941 us; speedup 1.0000x reference)
//
#include <hip/hip_runtime.h>
#include <hip/hip_bf16.h>
#include <stdint.h>

typedef __bf16 bf16;
typedef __bf16 bf16x8 __attribute__((ext_vector_type(8)));
typedef __bf16 bf16x4 __attribute__((ext_vector_type(4)));
typedef short  s16x4  __attribute__((ext_vector_type(4)));
typedef short  s16x8  __attribute__((ext_vector_type(8)));
typedef float  f32x4  __attribute__((ext_vector_type(4)));

#define N_B 4
#define N_T 2048
#define N_D 768
#define N_H 12
#define N_DH 64
#define M_TOT (N_B * N_T)   // 8192

// async global->LDS, 16 bytes per lane. LDS dest must be base + lane*16.
__device__ __forceinline__ void async_copy16(const bf16* g, bf16* l) {
    __builtin_amdgcn_global_load_lds(
        (const __attribute__((address_space(1))) unsigned int*)g,
        (__attribute__((address_space(3))) unsigned int*)l,
        16, 0, 0);
}

// fused fp32 -> bf16 convert for three arrays (each size % 1024 == 0)
__launch_bounds__(256)
__global__ void f2bf3(const float* __restrict__ a, bf16* __restrict__ oa, int na,
                      const float* __restrict__ b, bf16* __restrict__ ob, int nb,
                      const float* __restrict__ c, bf16* __restrict__ oc) {
    int i = (blockIdx.x * 256 + threadIdx.x) * 4;
    const float* src; bf16* dst;
    if (i < na)            { src = a; dst = oa; }
    else if (i < na + nb)  { src = b; dst = ob; i -= na; }
    else                   { src = c; dst = oc; i -= na + nb; }
    const float4 v = *(const float4*)(src + i);
    dst[i]     = (bf16)v.x;
    dst[i + 1] = (bf16)v.y;
    dst[i + 2] = (bf16)v.z;
    dst[i + 3] = (bf16)v.w;
}

// ---------------------------------------------------------------------------
// GEMM core: C[m,n] = sum_k A[m,k] * Bt[n,k]  (both K-contiguous, bf16)
// 128x128 tile, BK=32, 256 threads (4 waves, 2x2 of 64x64), 16x16x32 MFMA.
// smem pool (9216 bf16 = 18 KB): staging lsA/lsB during K-loop; reusable as
// a 128x72 transpose tile in epilogues.
// ---------------------------------------------------------------------------
#define GEMM_CORE(A_PTR, B_PTR, KDIM)                                          \
    __shared__ bf16 smem[9216];                                                \
    bf16* lsA = smem;                                                          \
    bf16* lsB = smem + 4096;                                                   \
    const int m0 = blockIdx.x * 128;                                           \
    const int n0 = blockIdx.y * 128;                                           \
    const int t  = threadIdx.x;                                                \
    const int w  = t >> 6, l = t & 63;                                         \
    const int wm = w & 1, wn = w >> 1;                                         \
    const int lr = l & 15, lq = l >> 4;                                        \
    f32x4 acc[4][4] = {};                                                      \
    const bf16* Ab = (A_PTR) + (size_t)(m0 + (t >> 2)) * (KDIM) + (t & 3) * 8; \
    const bf16* Bb = (B_PTR) + (size_t)(n0 + (t >> 2)) * (KDIM) + (t & 3) * 8; \
    bf16* lA = lsA + t * 8;                                                    \
    bf16* lB = lsB + t * 8;                                                    \
    for (int k0 = 0; k0 < (KDIM); k0 += 32) {                                  \
        __syncthreads();                                                       \
        async_copy16(Ab + k0, lA);                                             \
        async_copy16(Ab + (size_t)64 * (KDIM) + k0, lA + 2048);                \
        async_copy16(Bb + k0, lB);                                             \
        async_copy16(Bb + (size_t)64 * (KDIM) + k0, lB + 2048);                \
        __syncthreads();                                                       \
        bf16x8 af[4], bfr[4];                                                  \
        for (int i = 0; i < 4; i++) {                                          \
            af[i]  = *(const bf16x8*)(lsA + (wm * 64 + i * 16 + lr) * 32 + lq * 8); \
            bfr[i] = *(const bf16x8*)(lsB + (wn * 64 + i * 16 + lr) * 32 + lq * 8); \
        }                                                                      \
        for (int i = 0; i < 4; i++)                                            \
            for (int j = 0; j < 4; j++)                                        \
                acc[i][j] = __builtin_amdgcn_mfma_f32_16x16x32_bf16(           \
                    af[i], bfr[j], acc[i][j], 0, 0, 0);                        \
    }

// QKV projection: Xb * Wb^T + b_qkv.  768 = 6*128, so each block's n-range
// lies entirely in one of Q/K/V (which = n0/768, uniform per block).
// Q: [B,H,T,64] pre-scaled by 0.125*log2(e); K: [B,H,T,64] — both stored via
// a 2-pass LDS transpose -> b128 coalesced global stores (the old path was
// 2-byte scalar stores).  V: transposed [B,H,64,T] with keys PERMUTED inside
// each 64-token tile (idx(k) = (r>>2)*16 + kc*4 + (r&3)) so attn reads V
// A-frags as single b128.
__launch_bounds__(256)
__global__ void gemm_qkv(const bf16* __restrict__ X, const bf16* __restrict__ W,
                         const float* __restrict__ bias,
                         bf16* __restrict__ Q, bf16* __restrict__ K,
                         bf16* __restrict__ Vt) {
    GEMM_CORE(X, W, 768)
    const int which = n0 / 768;
    const int b_ = m0 >> 11, tt0 = m0 & 2047;   // tiles never straddle batch
    if (which == 2) {
        // V^T with in-tile key permutation
        for (int i = 0; i < 4; i++) {
            const int tt = tt0 + wm * 64 + i * 16 + lq * 4;
            const int tile = tt >> 6, kl = tt & 63;
            const int kc = kl >> 4, r = kl & 15;
            const int idx = ((r >> 2) << 4) + (kc << 2);   // + (r&3)=0..3
            for (int j = 0; j < 4; j++) {
                const int rem = n0 - 1536 + wn * 64 + j * 16 + lr;
                const int h = rem >> 6, d = rem & 63;
                const float bv = bias[n0 + wn * 64 + j * 16 + lr];
                bf16x4 v4;
                for (int r2 = 0; r2 < 4; r2++) v4[r2] = (bf16)(acc[i][j][r2] + bv);
                *(bf16x4*)(Vt + ((size_t)((b_ * N_H + h) * 64 + d)) * 2048
                           + tile * 64 + idx) = v4;
            }
        }
    } else {
        bf16* dst0 = (which == 0) ? Q : K;
        const float sc = (which == 0) ? 0.18033688f : 1.0f;  // 1/8 * log2(e)
        const int rem0 = n0 - which * 768;
        for (int p = 0; p < 2; p++) {
            __syncthreads();             // smem free (staging / previous pass)
            if (wn == p) {               // these 2 waves own cols p*64..p*64+63
                for (int i = 0; i < 4; i++)
                    for (int j = 0; j < 4; j++) {
                        const int cL = j * 16 + lr;
                        const float bv = bias[n0 + p * 64 + cL];
                        const int tokL = wm * 64 + i * 16 + lq * 4;
                        for (int r = 0; r < 4; r++)
                            smem[(tokL + r) * 72 + cL] =
                                (bf16)((acc[i][j][r] + bv) * sc);
                    }
            }
            __syncthreads();
            {   // coalesced b128 stores: thread -> (token, 32-d half)
                const int token = t >> 1, dh = (t & 1) * 32;
                const int h = (rem0 >> 6) + p;
                bf16* dp = dst0 + ((size_t)(((b_ * N_H + h) << 11) + tt0 + token)) * 64 + dh;
                const bf16* sp2 = smem + token * 72 + dh;
                for (int c = 0; c < 4; c++)
                    *(bf16x8*)(dp + c * 8) = *(const bf16x8*)(sp2 + c * 8);
            }
        }
    }
}

// Output projection: Ob[8192x768] * Wpb[768x768]^T + b_proj -> out fp32
__launch_bounds__(256)
__global__ void gemm_proj(const bf16* __restrict__ O, const bf16* __restrict__ W,
                          const float* __restrict__ bias, float* __restrict__ out) {
    GEMM_CORE(O, W, 768)
    for (int i = 0; i < 4; i++) {
        const int rowb = m0 + wm * 64 + i * 16 + lq * 4;
        for (int j = 0; j < 4; j++) {
            const int col  = n0 + wn * 64 + j * 16 + lr;
            const float bv = bias[col];
            for (int r = 0; r < 4; r++)
                out[(size_t)(rowb + r) * 768 + col] = acc[i][j][r] + bv;
        }
    }
}

// ---------------------------------------------------------------------------
// Flash attention: R11's pipelined structure, but K-fragments come DIRECTLY
// FROM GLOBAL (all 8 waves read identical K rows -> L1 broadcast; VMEM pipe
// was idle) — this halves the per-CU LDS read traffic (the heaviest pipe:
// ~61us of R11's 100us wall) and removes K staging entirely. V stays in LDS
// (triple-buffered, PV lags S by one tile). LDS = 24 KB.
// S^T = K Q^T (16x16x32): P^T lands in C-layout == B-operand of 16x16x16.
// O^T = V^T P^T in C-layout; l via ones-MFMA; fixed-shift softmax exp2(s).
// 512 thr = 8 waves x 16 q = 128 q/block; grid 768 XCD-swizzled.
// ---------------------------------------------------------------------------
__launch_bounds__(512, 6)
__global__ void attn(const bf16* __restrict__ Q, const bf16* __restrict__ K,
                     const bf16* __restrict__ Vt, bf16* __restrict__ O) {
    __shared__ bf16 lsV[3][64 * 64];
    const int bid = blockIdx.x;
    const int xcd = bid & 7, slot = bid >> 3;
    const int bh  = xcd + 8 * (slot >> 4);   // 0..47, 6 heads per XCD
    const int qt  = slot & 15;               // 0..15
    const int t = threadIdx.x, w = t >> 6, l = t & 63;
    const int lr = l & 15, lq = l >> 4;
    const bf16* Qh  = Q  + (size_t)bh * N_T * 64;
    const bf16* Kh  = K  + (size_t)bh * N_T * 64;
    const bf16* Vth = Vt + (size_t)bh * 64 * N_T;
    const int q0 = qt * 128 + w * 16;        // this wave's 16 q rows

    // V staging: thread t stages one 16B chunk per tile.
    const int sr = t >> 3;                   // 0..63
    const int sp = t & 7;                    // 0..7
    const int scn = sp ^ (sr & 7);           // XOR swizzle on source 16B unit

    // K A-frag base: row = kt*64 + ki*16 + lr, bytes ks*32 + lq*8
    const bf16* Kb = Kh + (size_t)lr * 64 + lq * 8;

    // Q fragments (B-operand, n=q=lr, k=d)
    bf16x8 qf[2];
    for (int ks = 0; ks < 2; ks++)
        qf[ks] = *(const bf16x8*)(Qh + (size_t)(q0 + lr) * 64 + ks * 32 + lq * 8);

    f32x4 oacc[4] = {};                      // O^T[d = dj*16+lq*4+r][q=lr]
    f32x4 lacc = {};                         // l(q) via ones-MFMA
    const s16x4 ones = {0x3F80, 0x3F80, 0x3F80, 0x3F80};  // bf16 1.0 x4

    // ---- prologue ----
    async_copy16(Vth + (size_t)sr * 2048 + scn * 8, lsV[0] + t * 8);
    __syncthreads();
    async_copy16(Vth + (size_t)sr * 2048 + 64 + scn * 8, lsV[1] + t * 8);

    f32x4 sprev[4] = {};                     // S^T(tile 0), K from global
    for (int ks = 0; ks < 2; ks++)
        for (int ki = 0; ki < 4; ki++) {
            bf16x8 kf = *(const bf16x8*)(Kb + ki * 1024 + ks * 32);
            sprev[ki] = __builtin_amdgcn_mfma_f32_16x16x32_bf16(
                kf, qf[ks], sprev[ki], 0, 0, 0);
        }

    int vprev = 0, vcur = 1, vnext = 2;      // V buffer rotation

    for (int i = 1; i < 32; i++) {
        __syncthreads();   // V(i) staged; all waves done reading lsV[vnext slot]

        if (i < 31)        // prefetch V(i+1)
            async_copy16(Vth + (size_t)sr * 2048 + (i + 1) * 64 + scn * 8,
                         lsV[vnext] + t * 8);

        // ---- S(i): K from global (L1-broadcast across the 8 waves) ----
        f32x4 snew[4] = {};
        for (int ks = 0; ks < 2; ks++)
            for (int ki = 0; ki < 4; ki++) {
                bf16x8 kf = *(const bf16x8*)(Kb + (size_t)i * 4096 + ki * 1024 + ks * 32);
                snew[ki] = __builtin_amdgcn_mfma_f32_16x16x32_bf16(
                    kf, qf[ks], snew[ki], 0, 0, 0);
            }

        // ---- exp(i-1) [VALU] ----
        s16x4 pbf[4];
        for (int ki = 0; ki < 4; ki++) {
            bf16x4 pb;
            for (int r = 0; r < 4; r++)
                pb[r] = (bf16)exp2f(sprev[ki][r]);
            pbf[ki] = __builtin_bit_cast(s16x4, pb);
        }

        // ---- PV(i-1) [matrix + LDS] ----
        const bf16* vb = lsV[vprev];
        for (int c = 0; c < 2; c++)
            for (int dj = 0; dj < 4; dj++) {
                const int unit = (2 * lq + c) ^ (lr & 7);
                s16x8 vv = *(const s16x8*)(vb + (dj * 16 + lr) * 64 + unit * 8);
                s16x4 vlo = __builtin_shufflevector(vv, vv, 0, 1, 2, 3);
                s16x4 vhi = __builtin_shufflevector(vv, vv, 4, 5, 6, 7);
                oacc[dj] = __builtin_amdgcn_mfma_f32_16x16x16bf16_1k(
                    vlo, pbf[2 * c], oacc[dj], 0, 0, 0);
                oacc[dj] = __builtin_amdgcn_mfma_f32_16x16x16bf16_1k(
                    vhi, pbf[2 * c + 1], oacc[dj], 0, 0, 0);
            }
        for (int kc = 0; kc < 4; kc++)
            lacc = __builtin_amdgcn_mfma_f32_16x16x16bf16_1k(
                ones, pbf[kc], lacc, 0, 0, 0);

        for (int ki = 0; ki < 4; ki++) sprev[ki] = snew[ki];
        const int tmp = vprev; vprev = vcur; vcur = vnext; vnext = tmp;
    }

    // ---- tail: exp(31) + PV(31) ----
    {
        s16x4 pbf[4];
        for (int ki = 0; ki < 4; ki++) {
            bf16x4 pb;
            for (int r = 0; r < 4; r++)
                pb[r] = (bf16)exp2f(sprev[ki][r]);
            pbf[ki] = __builtin_bit_cast(s16x4, pb);
        }
        const bf16* vb = lsV[vprev];
        for (int c = 0; c < 2; c++)
            for (int dj = 0; dj < 4; dj++) {
                const int unit = (2 * lq + c) ^ (lr & 7);
                s16x8 vv = *(const s16x8*)(vb + (dj * 16 + lr) * 64 + unit * 8);
                s16x4 vlo = __builtin_shufflevector(vv, vv, 0, 1, 2, 3);
                s16x4 vhi = __builtin_shufflevector(vv, vv, 4, 5, 6, 7);
                oacc[dj] = __builtin_amdgcn_mfma_f32_16x16x16bf16_1k(
                    vlo, pbf[2 * c], oacc[dj], 0, 0, 0);
                oacc[dj] = __builtin_amdgcn_mfma_f32_16x16x16bf16_1k(
                    vhi, pbf[2 * c + 1], oacc[dj], 0, 0, 0);
            }
        for (int kc = 0; kc < 4; kc++)
            lacc = __builtin_amdgcn_mfma_f32_16x16x16bf16_1k(
                ones, pbf[kc], lacc, 0, 0, 0);
    }

    // ---- epilogue: O^T/l -> O [B,T,H*64] bf16, 8B packed stores ----
    const int b = bh / N_H, h = bh - b * N_H;
    const float inv_l = 1.0f / lacc[0];
    const int tok = q0 + lr;
    bf16* Ob = O + ((size_t)b * N_T + tok) * N_D + h * 64;
    for (int dj = 0; dj < 4; dj++) {
        bf16x4 o4;
        for (int r = 0; r < 4; r++) o4[r] = (bf16)(oacc[dj][r] * inv_l);
        *(bf16x4*)(Ob + dj * 16 + lq * 4) = o4;
    }
}

extern "C" void kernel_launch(void* const* d_in, const int* in_sizes, int n_in,
                              void* d_out, int out_size, void* d_ws, size_t ws_size,
                              hipStream_t stream) {
    const float* x      = (const float*)d_in[0];
    const float* W_qkv  = (const float*)d_in[1];
    const float* b_qkv  = (const float*)d_in[2];
    const float* W_proj = (const float*)d_in[3];
    const float* b_proj = (const float*)d_in[4];
    float* out = (float*)d_out;

    char* ws = (char*)d_ws;
    const size_t n_x  = (size_t)M_TOT * N_D;        // 6291456
    const size_t n_wq = (size_t)3 * N_D * N_D;      // 1769472
    const size_t n_wp = (size_t)N_D * N_D;          // 589824
    const size_t sz_qkv = (size_t)N_B * N_H * N_T * N_DH * sizeof(bf16);  // 12.58 MB

    bf16* xb  = (bf16*)(ws);                 ws += n_x * sizeof(bf16);
    bf16* Wqb = (bf16*)(ws);                 ws += n_wq * sizeof(bf16);
    bf16* Wpb = (bf16*)(ws);                 ws += n_wp * sizeof(bf16);
    bf16* Qb  = (bf16*)(ws);                 ws += sz_qkv;
    bf16* Kb  = (bf16*)(ws);                 ws += sz_qkv;
    bf16* Vtb = (bf16*)(ws);                 ws += sz_qkv;
    bf16* Ob  = (bf16*)(ws);

    dim3 blk(256);
    f2bf3<<<dim3((int)((n_x + n_wq + n_wp) / 1024)), blk, 0, stream>>>(
        x, xb, (int)n_x, W_qkv, Wqb, (int)n_wq, W_proj, Wpb);

    gemm_qkv<<<dim3(M_TOT / 128, 2304 / 128), blk, 0, stream>>>(xb, Wqb, b_qkv, Qb, Kb, Vtb);
    attn<<<dim3(768), dim3(512), 0, stream>>>(Qb, Kb, Vtb, Ob);
    gemm_proj<<<dim3(M_TOT / 128, 768 / 128), blk, 0, stream>>>(Ob, Wpb, b_proj, out);
}